// Round 1
// baseline (1426.250 us; speedup 1.0000x reference)
//
#include <hip/hip_runtime.h>
#include <hip/hip_bf16.h>
#include <cstddef>

#define NN 1024
#define HH 12
#define SQK 16
#define SV 16
#define PQK 4
#define PV 8
#define C1 384
#define C2 128
#define COUT 384

#define HSQK (HH*SQK)            // 192
#define HKV  (HH*(SQK+SV))       // 384
#define QPF  (HH*3*PQK)          // 144
#define KVPF (HH*3*(PQK+PV))     // 432
#define FDIM (HH*(C2+SV+4*PV))   // 2112

__device__ __constant__ const float SCALAR_W  = 0.14433756729740643f; // 1/sqrt(48)
__device__ __constant__ const float POINT_W   = 0.13608276348795434f; // 1/sqrt(54)
__device__ __constant__ const float W2D_SCALE = 0.5773502691896258f;  // 1/sqrt(3)

// ---------------- workspace layout (float offsets) ----------------
constexpr size_t OFF_QS     = 0;                        // 1024*192
constexpr size_t OFF_KVS    = OFF_QS     + 196608;      // 1024*384
constexpr size_t OFF_QPF    = OFF_KVS    + 393216;      // 1024*144
constexpr size_t OFF_KVPF   = OFF_QPF    + 147456;      // 1024*432
constexpr size_t OFF_QPTG   = OFF_KVPF   + 442368;      // 1024*144
constexpr size_t OFF_KVPTG  = OFF_QPTG   + 147456;      // 1024*432
constexpr size_t OFF_Q2     = OFF_KVPTG  + 442368;      // 12*1024
constexpr size_t OFF_K2     = OFF_Q2     + 12288;       // 12*1024
constexpr size_t OFF_PW     = OFF_K2     + 12288;       // 64
constexpr size_t OFF_VT     = OFF_PW     + 64;          // 480*1024
constexpr size_t OFF_RESPTG = OFF_VT     + 491520;      // 1024*288
constexpr size_t OFF_FINAL  = OFF_RESPTG + 294912;      // 1024*2112
constexpr size_t OFF_LOGITS = OFF_FINAL  + 2162688;     // 12*1024*1024
// total = 17,326,144 floats = ~69.3 MB

// ---------------- generic 128x64 fp32 GEMM tile ----------------
template <bool ATOMIC>
__device__ void gemm_tile_128x64(const float* __restrict__ A, const float* __restrict__ W,
                                 const float* __restrict__ bias, float* __restrict__ C,
                                 int K, int Ncols, int m0, int n0, int k0, int ktiles,
                                 bool addbias)
{
    __shared__ float As[16][136]; // padded: rows 544B (16B-aligned), breaks conflicts
    __shared__ float Bs[16][68];  // rows 272B (16B-aligned)
    const int t  = threadIdx.x;
    const int tx = t & 15;   // col group (4 cols)
    const int ty = t >> 4;   // row group (8 rows)

    float acc[8][4];
#pragma unroll
    for (int i = 0; i < 8; ++i)
#pragma unroll
        for (int j = 0; j < 4; ++j) acc[i][j] = 0.f;

    for (int kt = 0; kt < ktiles; ++kt) {
        const int kb = k0 + kt * 16;
        // A tile: 128 rows x 16 k, loaded as 2 x float4 per thread, stored transposed
        {
            const int mi = t >> 1, k8 = (t & 1) * 8;
            const float* src = A + (size_t)(m0 + mi) * K + kb + k8;
            float4 v0 = *(const float4*)(src);
            float4 v1 = *(const float4*)(src + 4);
            As[k8 + 0][mi] = v0.x; As[k8 + 1][mi] = v0.y;
            As[k8 + 2][mi] = v0.z; As[k8 + 3][mi] = v0.w;
            As[k8 + 4][mi] = v1.x; As[k8 + 5][mi] = v1.y;
            As[k8 + 6][mi] = v1.z; As[k8 + 7][mi] = v1.w;
        }
        // B tile: 16 k x 64 cols
        {
            const int kk = t >> 4, n4 = (t & 15) * 4;
            const int col = n0 + n4;
            float4 v = make_float4(0.f, 0.f, 0.f, 0.f);
            if (col < Ncols) v = *(const float4*)(W + (size_t)(kb + kk) * Ncols + col);
            *(float4*)&Bs[kk][n4] = v;
        }
        __syncthreads();
#pragma unroll
        for (int kk = 0; kk < 16; ++kk) {
            float bv[4];
            *(float4*)bv = *(const float4*)&Bs[kk][tx * 4];
            float av[8];
            *(float4*)&av[0] = *(const float4*)&As[kk][ty * 8];
            *(float4*)&av[4] = *(const float4*)&As[kk][ty * 8 + 4];
#pragma unroll
            for (int i = 0; i < 8; ++i)
#pragma unroll
                for (int j = 0; j < 4; ++j) acc[i][j] += av[i] * bv[j];
        }
        __syncthreads();
    }
#pragma unroll
    for (int i = 0; i < 8; ++i) {
        const int row = m0 + ty * 8 + i;
#pragma unroll
        for (int j = 0; j < 4; ++j) {
            const int col = n0 + tx * 4 + j;
            if (col < Ncols) {
                float v = acc[i][j] + (addbias ? bias[col] : 0.f);
                if (ATOMIC) atomicAdd(&C[(size_t)row * Ncols + col], v);
                else        C[(size_t)row * Ncols + col] = v;
            }
        }
    }
}

// ---------------- 1: fused projection GEMMs ----------------
__global__ __launch_bounds__(256) void proj_kernel(
    const float* __restrict__ A,
    const float* __restrict__ wqs,  const float* __restrict__ bqs,
    const float* __restrict__ wkvs, const float* __restrict__ bkvs,
    const float* __restrict__ wqp,  const float* __restrict__ bqp,
    const float* __restrict__ wkvp, const float* __restrict__ bkvp,
    float* __restrict__ qs, float* __restrict__ kvs,
    float* __restrict__ qpf, float* __restrict__ kvpf)
{
    const int ct = blockIdx.x % 19;
    const int mt = blockIdx.x / 19;
    const float *W, *bias; float* C; int Ncols, n0;
    if (ct < 3)       { W = wqs;  bias = bqs;  C = qs;   Ncols = 192; n0 = ct * 64; }
    else if (ct < 9)  { W = wkvs; bias = bkvs; C = kvs;  Ncols = 384; n0 = (ct - 3) * 64; }
    else if (ct < 12) { W = wqp;  bias = bqp;  C = qpf;  Ncols = 144; n0 = (ct - 9) * 64; }
    else              { W = wkvp; bias = bkvp; C = kvpf; Ncols = 432; n0 = (ct - 12) * 64; }
    gemm_tile_128x64<false>(A, W, bias, C, C1, Ncols, mt * 128, n0, 0, 24, true);
}

// ---------------- 2: point transform, q2/k2, pw ----------------
__global__ __launch_bounds__(192) void points_kernel(
    const float* __restrict__ qpf, const float* __restrict__ kvpf,
    const float* __restrict__ rot, const float* __restrict__ trans,
    const float* __restrict__ tpw,
    float* __restrict__ qptg, float* __restrict__ kvptg,
    float* __restrict__ q2, float* __restrict__ k2, float* __restrict__ pw)
{
    __shared__ float lq[48 * 3];
    __shared__ float lkv[144 * 3];
    const int n = blockIdx.x, t = threadIdx.x;
    float r[9], tr[3];
#pragma unroll
    for (int i = 0; i < 9; ++i) r[i] = rot[n * 9 + i];
#pragma unroll
    for (int i = 0; i < 3; ++i) tr[i] = trans[n * 3 + i];

    if (t < 48) {
        float p0 = qpf[n * QPF + t], p1 = qpf[n * QPF + 48 + t], p2 = qpf[n * QPF + 96 + t];
#pragma unroll
        for (int i = 0; i < 3; ++i)
            lq[t * 3 + i] = r[i * 3 + 0] * p0 + r[i * 3 + 1] * p1 + r[i * 3 + 2] * p2 + tr[i];
    }
    if (t < 144) {
        float p0 = kvpf[(size_t)n * KVPF + t];
        float p1 = kvpf[(size_t)n * KVPF + 144 + t];
        float p2 = kvpf[(size_t)n * KVPF + 288 + t];
#pragma unroll
        for (int i = 0; i < 3; ++i)
            lkv[t * 3 + i] = r[i * 3 + 0] * p0 + r[i * 3 + 1] * p1 + r[i * 3 + 2] * p2 + tr[i];
    }
    __syncthreads();
    if (t < 48) {
#pragma unroll
        for (int i = 0; i < 3; ++i) qptg[(size_t)n * QPF + t * 3 + i] = lq[t * 3 + i];
    }
    if (t < 144) {
#pragma unroll
        for (int i = 0; i < 3; ++i) kvptg[(size_t)n * KVPF + t * 3 + i] = lkv[t * 3 + i];
    }
    if (t < HH) {
        float s = 0.f;
#pragma unroll
        for (int p = 0; p < 4; ++p)
#pragma unroll
            for (int i = 0; i < 3; ++i) { float v = lq[(t * 4 + p) * 3 + i]; s += v * v; }
        q2[t * NN + n] = s;
        float s2 = 0.f;
#pragma unroll
        for (int p = 0; p < 4; ++p)
#pragma unroll
            for (int i = 0; i < 3; ++i) { float v = lkv[(t * 12 + p) * 3 + i]; s2 += v * v; }
        k2[t * NN + n] = s2;
        if (n == 0) {
            float x = tpw[t];
            float sp = (x > 20.f) ? x : log1pf(__expf(x));
            pw[t] = sp * POINT_W;
        }
    }
}

// ---------------- 3: build transposed V table (480 x 1024) ----------------
__global__ __launch_bounds__(256) void vt_kernel(const float* __restrict__ kvs,
                                                 const float* __restrict__ kvptg,
                                                 float* __restrict__ vT)
{
    const int idx = blockIdx.x * 256 + threadIdx.x;  // 480*1024 total
    const int r = idx >> 10, m = idx & 1023;
    float val;
    if (r < 192) {
        const int h = r >> 4, c = r & 15;
        val = kvs[(size_t)m * HKV + h * 32 + 16 + c];
    } else {
        const int q = r - 192;
        const int h = q / 24, rem = q % 24;
        val = kvptg[(size_t)m * KVPF + h * 36 + 12 + rem];
    }
    vT[(size_t)r * NN + m] = val;
}

// ---------------- 4: logits (fused a2d + scalar QK + point QK + mask) ----------------
__global__ __launch_bounds__(256) void logits_kernel(
    const float* __restrict__ in2d, const float* __restrict__ w2d, const float* __restrict__ b2d,
    const float* __restrict__ qs, const float* __restrict__ kvs,
    const float* __restrict__ qptg, const float* __restrict__ kvptg,
    const float* __restrict__ q2, const float* __restrict__ k2,
    const float* __restrict__ pw, const float* __restrict__ mask,
    float* __restrict__ logits)
{
    __shared__ float w2s[C2 * HH]; // 1536
    const int t = threadIdx.x;
    for (int i = t; i < C2 * HH; i += 256) w2s[i] = w2d[i];
    __syncthreads();

    const int n = blockIdx.x >> 2;
    const int m = ((blockIdx.x & 3) << 8) + t;

    // a2d: dot of this (n,m) 2d row with the 12 w_2d columns
    const float4* row = (const float4*)(in2d + ((size_t)n * NN + m) * C2);
    float a2[HH];
#pragma unroll
    for (int h = 0; h < HH; ++h) a2[h] = 0.f;
    for (int c4 = 0; c4 < C2 / 4; ++c4) {
        float4 v = row[c4];
        const float* w = &w2s[c4 * 4 * HH];
#pragma unroll
        for (int h = 0; h < HH; ++h)
            a2[h] += v.x * w[h] + v.y * w[HH + h] + v.z * w[2 * HH + h] + v.w * w[3 * HH + h];
    }
    const float mval = -100000.f * (1.f - mask[n] * mask[m]);
    const float* qbase = qs + (size_t)n * HSQK;
    const float* kbase = kvs + (size_t)m * HKV;
    const float* qpb = qptg + (size_t)n * QPF;
    const float* kpb = kvptg + (size_t)m * KVPF;

    for (int h = 0; h < HH; ++h) {
        const float4* qq = (const float4*)(qbase + h * SQK);
        const float4* kq = (const float4*)(kbase + h * (SQK + SV));
        float sd = 0.f;
#pragma unroll
        for (int j = 0; j < 4; ++j) {
            float4 a = qq[j], b = kq[j];
            sd += a.x * b.x + a.y * b.y + a.z * b.z + a.w * b.w;
        }
        const float4* qp = (const float4*)(qpb + h * 3 * PQK);
        const float4* kp = (const float4*)(kpb + h * 3 * (PQK + PV));
        float cr = 0.f;
#pragma unroll
        for (int j = 0; j < 3; ++j) {
            float4 a = qp[j], b = kp[j];
            cr += a.x * b.x + a.y * b.y + a.z * b.z + a.w * b.w;
        }
        float pt = -0.5f * pw[h] * (q2[h * NN + n] + k2[h * NN + m] - 2.f * cr);
        float lg = SCALAR_W * sd + pt + W2D_SCALE * (a2[h] + b2d[h]) + mval;
        logits[((size_t)h * NN + n) * NN + m] = lg;
    }
}

// ---------------- 5: row softmax in place ----------------
__global__ __launch_bounds__(256) void softmax_kernel(float* __restrict__ logits)
{
    const size_t rowid = blockIdx.x; // h*N + n
    float* p = logits + rowid * NN;
    const int t = threadIdx.x;
    float4 v = ((float4*)p)[t];
    float mx = fmaxf(fmaxf(v.x, v.y), fmaxf(v.z, v.w));
#pragma unroll
    for (int o = 32; o; o >>= 1) mx = fmaxf(mx, __shfl_xor(mx, o));
    __shared__ float redm[4];
    __shared__ float reds[4];
    const int w = t >> 6, lane = t & 63;
    if (lane == 0) redm[w] = mx;
    __syncthreads();
    mx = fmaxf(fmaxf(redm[0], redm[1]), fmaxf(redm[2], redm[3]));
    float e0 = __expf(v.x - mx), e1 = __expf(v.y - mx), e2 = __expf(v.z - mx), e3 = __expf(v.w - mx);
    float s = e0 + e1 + e2 + e3;
#pragma unroll
    for (int o = 32; o; o >>= 1) s += __shfl_xor(s, o);
    if (lane == 0) reds[w] = s;
    __syncthreads();
    s = reds[0] + reds[1] + reds[2] + reds[3];
    const float inv = 1.f / s;
    ((float4*)p)[t] = make_float4(e0 * inv, e1 * inv, e2 * inv, e3 * inv);
}

// ---------------- 6: attn_2d (second inputs_2d pass) ----------------
__global__ __launch_bounds__(256) void attn2d_kernel(
    const float* __restrict__ attn, const float* __restrict__ in2d, float* __restrict__ fin)
{
    __shared__ float la[NN * HH]; // [m][h] 48 KB
    const int t = threadIdx.x;
    const int n = blockIdx.x;
#pragma unroll
    for (int h = 0; h < HH; ++h)
#pragma unroll
        for (int k = 0; k < 4; ++k) {
            const int m = t + (k << 8);
            la[m * HH + h] = attn[((size_t)h * NN + n) * NN + m];
        }
    __syncthreads();

    const int c0 = t & 31;
    const int ml = t >> 5; // 0..7
    float acc[HH][4];
#pragma unroll
    for (int h = 0; h < HH; ++h)
#pragma unroll
        for (int j = 0; j < 4; ++j) acc[h][j] = 0.f;

    const float* base = in2d + (size_t)n * NN * C2;
    for (int m = ml; m < NN; m += 8) {
        const float* r2 = base + (size_t)m * C2;
        float v0 = r2[c0], v1 = r2[c0 + 32], v2 = r2[c0 + 64], v3 = r2[c0 + 96];
        const float* am = &la[m * HH];
        float av[HH];
        *(float4*)&av[0] = *(const float4*)(am);
        *(float4*)&av[4] = *(const float4*)(am + 4);
        *(float4*)&av[8] = *(const float4*)(am + 8);
#pragma unroll
        for (int h = 0; h < HH; ++h) {
            acc[h][0] += av[h] * v0; acc[h][1] += av[h] * v1;
            acc[h][2] += av[h] * v2; acc[h][3] += av[h] * v3;
        }
    }
    // reduce 8 m-lanes per (h, c); reuse la as [8][128] scratch
    for (int h = 0; h < HH; ++h) {
        __syncthreads();
        la[(ml << 7) + c0]      = acc[h][0];
        la[(ml << 7) + c0 + 32] = acc[h][1];
        la[(ml << 7) + c0 + 64] = acc[h][2];
        la[(ml << 7) + c0 + 96] = acc[h][3];
        __syncthreads();
        if (t < 128) {
            float s = 0.f;
#pragma unroll
            for (int l = 0; l < 8; ++l) s += la[(l << 7) + t];
            fin[(size_t)n * FDIM + 576 + (h << 7) + t] = s;
        }
    }
}

// ---------------- 7: attn @ V (scalar + points, via transposed V) ----------------
__global__ __launch_bounds__(256) void attnv_kernel(
    const float* __restrict__ attn, const float* __restrict__ vT,
    float* __restrict__ fin, float* __restrict__ resptg)
{
    __shared__ float la[HH * 1040]; // [h][m], padded row 1040 (16B-aligned, conflict-free)
    const int t = threadIdx.x;
    const int n = blockIdx.x;
#pragma unroll
    for (int h = 0; h < HH; ++h)
#pragma unroll
        for (int k = 0; k < 4; ++k) {
            const int m = t + (k << 8);
            la[h * 1040 + m] = attn[((size_t)h * NN + n) * NN + m];
        }
    __syncthreads();
    for (int r = t; r < 480; r += 256) {
        const int h = (r < 192) ? (r >> 4) : ((r - 192) / 24);
        const float4* vr = (const float4*)(vT + (size_t)r * NN);
        const float4* ar = (const float4*)&la[h * 1040];
        float s = 0.f;
        for (int q = 0; q < NN / 4; ++q) {
            float4 a = ar[q], v = vr[q];
            s += a.x * v.x + a.y * v.y + a.z * v.z + a.w * v.w;
        }
        if (r < 192) fin[(size_t)n * FDIM + r] = s;
        else         resptg[(size_t)n * 288 + (r - 192)] = s;
    }
}

// ---------------- 8: invert point transform, dist, write into final ----------------
__global__ __launch_bounds__(128) void ptout_kernel(
    const float* __restrict__ resptg, const float* __restrict__ rot,
    const float* __restrict__ trans, float* __restrict__ fin)
{
    const int n = blockIdx.x, t = threadIdx.x;
    if (t >= 96) return;
    float g0 = resptg[(size_t)n * 288 + t * 3 + 0];
    float g1 = resptg[(size_t)n * 288 + t * 3 + 1];
    float g2 = resptg[(size_t)n * 288 + t * 3 + 2];
    float d0 = g0 - trans[n * 3 + 0];
    float d1 = g1 - trans[n * 3 + 1];
    float d2 = g2 - trans[n * 3 + 2];
    // l_i = sum_j rot[j][i] * d[j]  (R^T d)
    float l0 = rot[n * 9 + 0] * d0 + rot[n * 9 + 3] * d1 + rot[n * 9 + 6] * d2;
    float l1 = rot[n * 9 + 1] * d0 + rot[n * 9 + 4] * d1 + rot[n * 9 + 7] * d2;
    float l2 = rot[n * 9 + 2] * d0 + rot[n * 9 + 5] * d1 + rot[n * 9 + 8] * d2;
    const size_t base = (size_t)n * FDIM;
    fin[base + 192 + t] = l0;
    fin[base + 288 + t] = l1;
    fin[base + 384 + t] = l2;
    fin[base + 480 + t] = sqrtf(1e-8f + l0 * l0 + l1 * l1 + l2 * l2);
}

// ---------------- 9: final GEMM (K-split + atomics) ----------------
__global__ __launch_bounds__(256) void outgemm_kernel(
    const float* __restrict__ fin, const float* __restrict__ wout,
    const float* __restrict__ bout, float* __restrict__ out)
{
    const int n0 = blockIdx.x * 64;
    const int m0 = blockIdx.y * 128;
    const int z  = blockIdx.z;
    gemm_tile_128x64<true>(fin, wout, bout, out, FDIM, COUT, m0, n0, z * 352, 22, z == 0);
}

extern "C" void kernel_launch(void* const* d_in, const int* in_sizes, int n_in,
                              void* d_out, int out_size, void* d_ws, size_t ws_size,
                              hipStream_t stream)
{
    const float* in1d  = (const float*)d_in[0];
    const float* in2d  = (const float*)d_in[1];
    const float* mask  = (const float*)d_in[2];
    const float* rot   = (const float*)d_in[3];
    const float* trans = (const float*)d_in[4];
    const float* wqs   = (const float*)d_in[5];
    const float* bqs   = (const float*)d_in[6];
    const float* wkvs  = (const float*)d_in[7];
    const float* bkvs  = (const float*)d_in[8];
    const float* wqp   = (const float*)d_in[9];
    const float* bqp   = (const float*)d_in[10];
    const float* bkvpW = (const float*)d_in[11]; // w_kv_point
    const float* bkvpB = (const float*)d_in[12]; // b_kv_point
    const float* w2d   = (const float*)d_in[13];
    const float* b2d   = (const float*)d_in[14];
    const float* tpw   = (const float*)d_in[15];
    const float* wout  = (const float*)d_in[16];
    const float* bout  = (const float*)d_in[17];

    float* ws     = (float*)d_ws;
    float* qs     = ws + OFF_QS;
    float* kvs    = ws + OFF_KVS;
    float* qpf    = ws + OFF_QPF;
    float* kvpf   = ws + OFF_KVPF;
    float* qptg   = ws + OFF_QPTG;
    float* kvptg  = ws + OFF_KVPTG;
    float* q2     = ws + OFF_Q2;
    float* k2     = ws + OFF_K2;
    float* pw     = ws + OFF_PW;
    float* vT     = ws + OFF_VT;
    float* resptg = ws + OFF_RESPTG;
    float* fin    = ws + OFF_FINAL;
    float* logits = ws + OFF_LOGITS;

    // output accumulated atomically by the K-split final GEMM -> zero it first
    hipMemsetAsync(d_out, 0, (size_t)out_size * sizeof(float), stream);

    proj_kernel<<<152, 256, 0, stream>>>(in1d, wqs, bqs, wkvs, bkvs, wqp, bqp, bkvpW, bkvpB,
                                         qs, kvs, qpf, kvpf);
    points_kernel<<<NN, 192, 0, stream>>>(qpf, kvpf, rot, trans, tpw, qptg, kvptg, q2, k2, pw);
    vt_kernel<<<1920, 256, 0, stream>>>(kvs, kvptg, vT);
    logits_kernel<<<4096, 256, 0, stream>>>(in2d, w2d, b2d, qs, kvs, qptg, kvptg,
                                            q2, k2, pw, mask, logits);
    softmax_kernel<<<HH * NN, 256, 0, stream>>>(logits);
    attn2d_kernel<<<NN, 256, 0, stream>>>(logits, in2d, fin);
    attnv_kernel<<<NN, 256, 0, stream>>>(logits, vT, fin, resptg);
    ptout_kernel<<<NN, 128, 0, stream>>>(resptg, rot, trans, fin);
    outgemm_kernel<<<dim3(6, 8, 6), 256, 0, stream>>>(fin, wout, bout, (float*)d_out);
}